// Round 1
// baseline (4747.947 us; speedup 1.0000x reference)
//
#include <hip/hip_runtime.h>
#include <math.h>

#define NXY 513
#define NIN 511
#define NL3 3
#define NE4 4
#define NB 12            // NE4*NL3
#define GLD 512          // padded DST size / leading dim

static constexpr long FS  = (long)NE4 * NL3 * NXY * NXY;   // 3,158,028 floats per field
static constexpr long GSZ = (long)NB * GLD * GLD;          // 3,145,728
static constexpr int  NSTEPS = 4;

static constexpr double dF0 = 9.375e-05;
static constexpr double dDX = 10000.0;
static constexpr float ZFBCf     = (float)(0.2 / (1.0 + 0.5 * 0.2));
static constexpr float JACCf     = (float)(1.0 / (dF0 * dDX * dDX));
static constexpr float HYPCf     = (float)(2.0e9 / (dF0 * dF0) / (dDX*dDX*dDX*dDX*dDX*dDX));
static constexpr float BFCf      = (float)(2.0 / (2.0 * dF0 * dDX * dDX * (-2900.0)));
static constexpr float INVF0DX2f = (float)(1.0 / ((dF0 * dDX) * (dF0 * dDX)));

// ---------------- DST matrix init: S[n*512+k] = (1/16) sin(pi (n+1)(k+1) / 512), zero-padded ----
__global__ void initS_kernel(float* __restrict__ S) {
    int k = blockIdx.x * 256 + threadIdx.x;   // 0..511
    int n = blockIdx.y;                       // 0..511
    if (k >= GLD || n >= GLD) return;
    float v = 0.f;
    if (n < NIN && k < NIN) {
        int m = ((n + 1) * (k + 1)) & 1023;   // sin(pi*m/512) has period 1024 in m
        v = (float)(0.0625 * sin(M_PI * (double)m / 512.0));
    }
    S[n * GLD + k] = v;
}

// ---------------- laplacian_h with free-slip BC (fc = ZFBC), full 513x513 -----------------------
__global__ void lap_kernel(float* __restrict__ out, const float* __restrict__ f) {
    int y = blockIdx.x * blockDim.x + threadIdx.x;
    int x = blockIdx.y * blockDim.y + threadIdx.y;
    int c = blockIdx.z;  // e*3+l
    if (x >= NXY || y >= NXY) return;
    const float* fp = f + (size_t)c * NXY * NXY;
    float* op = out + (size_t)c * NXY * NXY;
    float v;
    if (y == 0)            v = ZFBCf * (fp[x*NXY + 1]       - fp[x*NXY + 0]);
    else if (y == NXY-1)   v = ZFBCf * (fp[x*NXY + NXY-2]   - fp[x*NXY + NXY-1]);
    else if (x == 0)       v = ZFBCf * (fp[1*NXY + y]       - fp[0*NXY + y]);
    else if (x == NXY-1)   v = ZFBCf * (fp[(NXY-2)*NXY + y] - fp[(NXY-1)*NXY + y]);
    else v = fp[(x+1)*NXY+y] + fp[(x-1)*NXY+y] + fp[x*NXY+y+1] + fp[x*NXY+y-1] - 4.f*fp[x*NXY+y];
    op[x*NXY + y] = v;
}

// ---------------- interior RHS: Jacobian + hyperdiff + wind + bottom friction; boundary = 0 -----
__global__ void rhs_kernel(float* __restrict__ kq, const float* __restrict__ q,
                           const float* __restrict__ p, const float* __restrict__ L2,
                           const float* __restrict__ wind) {
    int y = blockIdx.x * blockDim.x + threadIdx.x;
    int x = blockIdx.y * blockDim.y + threadIdx.y;
    int c = blockIdx.z;
    if (x >= NXY || y >= NXY) return;
    size_t off = (size_t)c * NXY * NXY;
    float* outp = kq + off;
    if (x == 0 || x == NXY-1 || y == 0 || y == NXY-1) { outp[x*NXY + y] = 0.f; return; }
#define IDX(i,j) ((i)*NXY + (j))
    const float* f = q + off;
    const float* g = p + off;
    float fmm=f[IDX(x-1,y-1)], fm0=f[IDX(x-1,y)], fmp=f[IDX(x-1,y+1)];
    float f0m=f[IDX(x,  y-1)],                     f0p=f[IDX(x,  y+1)];
    float fpm=f[IDX(x+1,y-1)], fp0=f[IDX(x+1,y)], fpp=f[IDX(x+1,y+1)];
    float gmm=g[IDX(x-1,y-1)], gm0=g[IDX(x-1,y)], gmp=g[IDX(x-1,y+1)];
    float g0m=g[IDX(x,  y-1)], g00=g[IDX(x,  y)], g0p=g[IDX(x,  y+1)];
    float gpm=g[IDX(x+1,y-1)], gp0=g[IDX(x+1,y)], gpp=g[IDX(x+1,y+1)];
    float J1 = (fp0 - fm0) * (g0p - g0m) - (gp0 - gm0) * (f0p - f0m);
    float J2 = fp0 * (gpp - gpm) - fm0 * (gmp - gmm);
    float J3 = f0p * (gpp - gmp) - f0m * (gpm - gmm);
    float J4 = g0p * (fpp - fmp) - g0m * (fpm - fmm);
    float J5 = gp0 * (fpp - fpm) - gm0 * (fmp - fmm);
    float jac = (J1 + J2 - J3 + J4 - J5) * (1.0f / 12.0f);
    float lap2 = L2[off+IDX(x+1,y)] + L2[off+IDX(x-1,y)] + L2[off+IDX(x,y+1)] + L2[off+IDX(x,y-1)]
               - 4.f * L2[off+IDX(x,y)];
    float v = JACCf * jac - HYPCf * lap2;
    int l = c % NL3;
    if (l == 0)     v += wind[(x-1)*NIN + (y-1)];
    if (l == NL3-1) v += BFCf * (gp0 + gm0 + g0p + g0m - 4.f * g00);
    outp[IDX(x,y)] = v;
#undef IDX
}

// ---------------- layer->mode transform of interior, into compact 512x512 (pad zeroed) ----------
__global__ void l2m_kernel(float* __restrict__ G, const float* __restrict__ kq,
                           const float* __restrict__ Cl2m) {
    int ry = blockIdx.x * blockDim.x + threadIdx.x;  // 0..511
    int rx = blockIdx.y * blockDim.y + threadIdx.y;  // 0..511
    int e = blockIdx.z;
    size_t go = (size_t)(e * NL3) * GLD * GLD + (size_t)rx * GLD + ry;
    if (rx >= NIN || ry >= NIN) {
        G[go] = 0.f; G[go + GLD*GLD] = 0.f; G[go + 2*GLD*GLD] = 0.f;
        return;
    }
    size_t base = ((size_t)(e * NL3) * NXY + (rx + 1)) * NXY + (ry + 1);
    float f0 = kq[base];
    float f1 = kq[base + (size_t)NXY*NXY];
    float f2 = kq[base + 2*(size_t)NXY*NXY];
    G[go]             = Cl2m[0]*f0 + Cl2m[1]*f1 + Cl2m[2]*f2;
    G[go +   GLD*GLD] = Cl2m[3]*f0 + Cl2m[4]*f1 + Cl2m[5]*f2;
    G[go + 2*GLD*GLD] = Cl2m[6]*f0 + Cl2m[7]*f1 + Cl2m[8]*f2;
}

// ---------------- fp32 tiled GEMM: C[b] = A[b] * B[b], 512x512x512, optional helmholtz divide ---
__global__ __launch_bounds__(256) void dst_gemm(
    const float* __restrict__ A, const float* __restrict__ B, float* __restrict__ C,
    long sA, long sB, long sC, const float* __restrict__ helm)
{
    __shared__ float As[16][68];  // As[k][m]
    __shared__ float Bs[16][68];  // Bs[k][n]
    const int b = blockIdx.z;
    const float* Ab = A + (long)b * sA;
    const float* Bb = B + (long)b * sB;
    float*       Cb = C + (long)b * sC;
    const int t  = threadIdx.x;
    const int tx = t & 15, ty = t >> 4;
    const int m0 = blockIdx.x << 6, n0 = blockIdx.y << 6;
    const int lac = t & 15, lar = t >> 4;   // A tile loader: k=lac, m=lar+{0,16,32,48}
    const int lbj = t & 63, lbk = t >> 6;   // B tile loader: n=lbj, k=lbk+{0,4,8,12}
    float acc[4][4] = {};
    for (int k0 = 0; k0 < GLD; k0 += 16) {
#pragma unroll
        for (int u = 0; u < 4; ++u)
            As[lac][lar + 16*u] = Ab[(size_t)(m0 + lar + 16*u) * GLD + k0 + lac];
#pragma unroll
        for (int u = 0; u < 4; ++u)
            Bs[lbk + 4*u][lbj] = Bb[(size_t)(k0 + lbk + 4*u) * GLD + n0 + lbj];
        __syncthreads();
#pragma unroll
        for (int kk = 0; kk < 16; ++kk) {
            float a[4], bb[4];
#pragma unroll
            for (int i = 0; i < 4; ++i) a[i]  = As[kk][ty*4 + i];
#pragma unroll
            for (int j = 0; j < 4; ++j) bb[j] = Bs[kk][tx*4 + j];
#pragma unroll
            for (int i = 0; i < 4; ++i)
#pragma unroll
                for (int j = 0; j < 4; ++j) acc[i][j] += a[i] * bb[j];
        }
        __syncthreads();
    }
    const float* h = helm ? (helm + (size_t)(b % NL3) * NIN * NIN) : nullptr;
#pragma unroll
    for (int i = 0; i < 4; ++i) {
        int m = m0 + ty*4 + i;
#pragma unroll
        for (int j = 0; j < 4; ++j) {
            int n = n0 + tx*4 + j;
            float v = acc[i][j];
            if (h && m < NIN && n < NIN) v /= h[m*NIN + n];
            Cb[(size_t)m * GLD + n] = v;
        }
    }
}

// ---------------- per-(e,mode<2) partial sums of dp_modes interior -----------------------------
__global__ void mean_kernel(float* __restrict__ partial, const float* __restrict__ G) {
    int gy = blockIdx.y;                 // 0..7 : e*2+m
    int e = gy >> 1, m = gy & 1;
    const float* g = G + (size_t)(e * NL3 + m) * GLD * GLD;
    float s = 0.f;
    for (int idx = blockIdx.x * 256 + threadIdx.x; idx < GLD*GLD; idx += 64 * 256)
        s += g[idx];
    __shared__ float red[256];
    red[threadIdx.x] = s; __syncthreads();
    for (int w = 128; w >= 1; w >>= 1) {
        if (threadIdx.x < w) red[threadIdx.x] += red[threadIdx.x + w];
        __syncthreads();
    }
    if (threadIdx.x == 0) partial[gy * 64 + blockIdx.x] = red[0];
}

__global__ void dalpha_kernel(float* __restrict__ dal, const float* __restrict__ partial,
                              const float* __restrict__ alpha) {
    int t = threadIdx.x;
    if (t >= 8) return;
    int e = t >> 1, i = t & 1;
    float s0 = 0.f, s1 = 0.f;
    for (int bk = 0; bk < 64; ++bk) { s0 += partial[(e*2+0)*64 + bk]; s1 += partial[(e*2+1)*64 + bk]; }
    const float inv = 1.0f / ((float)NXY * (float)NXY);
    dal[t] = alpha[i*2+0] * (s0 * inv) + alpha[i*2+1] * (s1 * inv);
}

// ---------------- mode->layer: dp = Cm2l @ (pad(dp_modes) + dalpha*hom_sol) --------------------
__global__ void m2l_kernel(float* __restrict__ kp, const float* __restrict__ G,
                           const float* __restrict__ dal, const float* __restrict__ hom,
                           const float* __restrict__ Cm2l) {
    int y = blockIdx.x * blockDim.x + threadIdx.x;
    int x = blockIdx.y * blockDim.y + threadIdx.y;
    int e = blockIdx.z;
    if (x >= NXY || y >= NXY) return;
    float mv[3];
    bool interior = (x >= 1 && x <= NIN && y >= 1 && y <= NIN);
#pragma unroll
    for (int i = 0; i < 3; ++i)
        mv[i] = interior ? G[(size_t)(e*NL3 + i) * GLD * GLD + (size_t)(x-1) * GLD + (y-1)] : 0.f;
    float h0 = hom[(size_t)x * NXY + y];
    float h1 = hom[(size_t)NXY*NXY + (size_t)x * NXY + y];
    mv[0] += dal[e*2 + 0] * h0;
    mv[1] += dal[e*2 + 1] * h1;
#pragma unroll
    for (int l = 0; l < 3; ++l)
        kp[((size_t)(e*NL3 + l) * NXY + x) * NXY + y] =
            Cm2l[l*3+0]*mv[0] + Cm2l[l*3+1]*mv[1] + Cm2l[l*3+2]*mv[2];
}

// ---------------- boundary dq from dp ----------------------------------------------------------
__global__ void bound_kernel(float* __restrict__ kq, const float* __restrict__ kp,
                             const float* __restrict__ Amat) {
    int pos = blockIdx.x * 256 + threadIdx.x;   // 0..2047
    int e = blockIdx.y;
    if (pos >= 2048) return;
    int x, y, xn, yn;
    if (pos < NIN)            { x = 0;      y = pos + 1;        xn = 1;      yn = y; }
    else if (pos < 2*NIN)     { x = NXY-1;  y = pos - NIN + 1;  xn = NXY-2;  yn = y; }
    else if (pos < 2*NIN+NXY) { x = pos - 2*NIN;       y = 0;      xn = x; yn = 1; }
    else                      { x = pos - (2*NIN+NXY); y = NXY-1;  xn = x; yn = NXY-2; }
    float dpb[3], lpb[3];
#pragma unroll
    for (int j = 0; j < 3; ++j) {
        const float* f = kp + (size_t)(e*NL3 + j) * NXY * NXY;
        float c = f[(size_t)x * NXY + y];
        float nb = f[(size_t)xn * NXY + yn];
        dpb[j] = c;
        lpb[j] = ZFBCf * INVF0DX2f * (nb - c);
    }
#pragma unroll
    for (int l = 0; l < 3; ++l) {
        float v = lpb[l] - (Amat[l*3+0]*dpb[0] + Amat[l*3+1]*dpb[1] + Amat[l*3+2]*dpb[2]);
        kq[((size_t)(e*NL3 + l) * NXY + x) * NXY + y] = v;
    }
}

// ---------------- vectorized out = x + coef*dt*k  (dt = t[s+1]-t[s]) ---------------------------
__global__ void axpy_kernel(float4* __restrict__ out, const float4* __restrict__ xv,
                            const float4* __restrict__ kv, float coef,
                            const float* __restrict__ t, int s, long n4) {
    float c = coef * (t[s+1] - t[s]);
    for (long i = (long)blockIdx.x * blockDim.x + threadIdx.x; i < n4;
         i += (long)gridDim.x * blockDim.x) {
        float4 a = xv[i], b = kv[i];
        out[i] = make_float4(a.x + c*b.x, a.y + c*b.y, a.z + c*b.z, a.w + c*b.w);
    }
}

__global__ void copy_kernel(float4* __restrict__ out, const float4* __restrict__ in, long n4) {
    for (long i = (long)blockIdx.x * blockDim.x + threadIdx.x; i < n4;
         i += (long)gridDim.x * blockDim.x)
        out[i] = in[i];
}

// ===============================================================================================
extern "C" void kernel_launch(void* const* d_in, const int* in_sizes, int n_in,
                              void* d_out, int out_size, void* d_ws, size_t ws_size,
                              hipStream_t stream) {
    const float* y0    = (const float*)d_in[0];
    const float* tarr  = (const float*)d_in[1];
    const float* Amat  = (const float*)d_in[2];
    const float* Cl2m  = (const float*)d_in[3];
    const float* Cm2l  = (const float*)d_in[4];
    const float* helm  = (const float*)d_in[5];
    const float* alpha = (const float*)d_in[6];
    const float* hom   = (const float*)d_in[7];
    const float* wind  = (const float*)d_in[8];
    float* out = (float*)d_out;
    float* ws  = (float*)d_ws;

    float* S       = ws;                      // 262144
    float* ytmp    = S + (long)GLD*GLD;       // 2*FS
    float* kbuf    = ytmp + 2*FS;             // 2*FS
    float* R1      = kbuf + 2*FS;             // FS   (L1, then G0)
    float* R2      = R1 + FS;                 // FS   (L2, then G1)
    float* partial = R2 + FS;                 // 512
    float* dal     = partial + 512;           // 8

    const dim3 bSt(64, 4, 1);
    const dim3 gSt((NXY + 63)/64, (NXY + 3)/4, NB);
    const dim3 gSt4((NXY + 63)/64, (NXY + 3)/4, NE4);
    const dim3 gL2M(8, 128, NE4);
    const dim3 gG(8, 8, NB);
    const long n4 = 2*FS/4;

    initS_kernel<<<dim3(2, GLD), 256, 0, stream>>>(S);
    copy_kernel<<<1024, 256, 0, stream>>>((float4*)out, (const float4*)y0, n4);

    auto deriv = [&](const float* y, float* k) {
        const float* q = y;  const float* p = y + FS;
        float* kq = k;       float* kp = k + FS;
        lap_kernel<<<gSt, bSt, 0, stream>>>(R1, p);                 // L1 = lap_bc(p)
        lap_kernel<<<gSt, bSt, 0, stream>>>(R2, R1);                // L2 = lap_bc(L1)
        rhs_kernel<<<gSt, bSt, 0, stream>>>(kq, q, p, R2, wind);    // interior rhs -> kq
        l2m_kernel<<<gL2M, bSt, 0, stream>>>(R1, kq, Cl2m);         // G0 = Cl2m @ kq (interior)
        dst_gemm<<<gG, 256, 0, stream>>>(R1, S, R2, GLD*GLD, 0, GLD*GLD, nullptr);   // G1 = G0*S
        dst_gemm<<<gG, 256, 0, stream>>>(S, R2, R1, 0, GLD*GLD, GLD*GLD, helm);      // G0 = (S*G1)/helm
        dst_gemm<<<gG, 256, 0, stream>>>(R1, S, R2, GLD*GLD, 0, GLD*GLD, nullptr);   // G1 = G0*S
        dst_gemm<<<gG, 256, 0, stream>>>(S, R2, R1, 0, GLD*GLD, GLD*GLD, nullptr);   // G0 = S*G1
        mean_kernel<<<dim3(64, 8), 256, 0, stream>>>(partial, R1);
        dalpha_kernel<<<1, 64, 0, stream>>>(dal, partial, alpha);
        m2l_kernel<<<gSt4, bSt, 0, stream>>>(kp, R1, dal, hom, Cm2l);
        bound_kernel<<<dim3(8, NE4), 256, 0, stream>>>(kq, kp, Amat);
    };

    for (int s = 0; s < NSTEPS; ++s) {
        float* ycur  = out + (size_t)s * 2 * FS;
        float* ynext = out + (size_t)(s + 1) * 2 * FS;
        // k1
        deriv(ycur, kbuf);
        axpy_kernel<<<1024, 256, 0, stream>>>((float4*)ynext, (const float4*)ycur,
                                              (const float4*)kbuf, 1.f/6.f, tarr, s, n4);
        axpy_kernel<<<1024, 256, 0, stream>>>((float4*)ytmp, (const float4*)ycur,
                                              (const float4*)kbuf, 0.5f, tarr, s, n4);
        // k2
        deriv(ytmp, kbuf);
        axpy_kernel<<<1024, 256, 0, stream>>>((float4*)ynext, (const float4*)ynext,
                                              (const float4*)kbuf, 2.f/6.f, tarr, s, n4);
        axpy_kernel<<<1024, 256, 0, stream>>>((float4*)ytmp, (const float4*)ycur,
                                              (const float4*)kbuf, 0.5f, tarr, s, n4);
        // k3
        deriv(ytmp, kbuf);
        axpy_kernel<<<1024, 256, 0, stream>>>((float4*)ynext, (const float4*)ynext,
                                              (const float4*)kbuf, 2.f/6.f, tarr, s, n4);
        axpy_kernel<<<1024, 256, 0, stream>>>((float4*)ytmp, (const float4*)ycur,
                                              (const float4*)kbuf, 1.f, tarr, s, n4);
        // k4
        deriv(ytmp, kbuf);
        axpy_kernel<<<1024, 256, 0, stream>>>((float4*)ynext, (const float4*)ynext,
                                              (const float4*)kbuf, 1.f/6.f, tarr, s, n4);
    }
}

// Round 2
// 4383.089 us; speedup vs baseline: 1.0832x; 1.0832x over previous
//
#include <hip/hip_runtime.h>
#include <math.h>

#define NXY 513
#define NIN 511
#define NL3 3
#define NE4 4
#define NB 12
#define GLD 512

static constexpr long FS  = (long)NE4 * NL3 * NXY * NXY;   // 3,158,028 floats
static constexpr long GSZ = (long)NB * GLD * GLD;          // 3,145,728 elements
static constexpr int  NSTEPS = 4;

static constexpr double dF0 = 9.375e-05;
static constexpr double dDX = 10000.0;
static constexpr float ZFBCf     = (float)(0.2 / (1.0 + 0.5 * 0.2));
static constexpr float JACCf     = (float)(1.0 / (dF0 * dDX * dDX));
static constexpr float HYPCf     = (float)(2.0e9 / (dF0 * dF0) / (dDX*dDX*dDX*dDX*dDX*dDX));
static constexpr float BFCf      = (float)(2.0 / (2.0 * dF0 * dDX * dDX * (-2900.0)));
static constexpr float INVF0DX2f = (float)(1.0 / ((dF0 * dDX) * (dF0 * dDX)));

typedef short  bf16x8 __attribute__((ext_vector_type(8)));
typedef float  f32x4  __attribute__((ext_vector_type(4)));

__device__ __forceinline__ unsigned short f2bf(float x) {
    unsigned int u = __float_as_uint(x);
    return (unsigned short)((u + 0x7FFFu + ((u >> 16) & 1u)) >> 16);
}
__device__ __forceinline__ float bf2f(unsigned short h) {
    return __uint_as_float(((unsigned int)h) << 16);
}

// ---------------- DST matrix (bf16 hi/lo): S[n][k] = (1/16) sin(pi (n+1)(k+1)/512), zero-padded --
__global__ void initS_kernel(unsigned short* __restrict__ Sh, unsigned short* __restrict__ Sl) {
    int k = blockIdx.x * 256 + threadIdx.x;
    int n = blockIdx.y;
    if (k >= GLD || n >= GLD) return;
    float v = 0.f;
    if (n < NIN && k < NIN) {
        int m = ((n + 1) * (k + 1)) & 1023;
        v = (float)(0.0625 * sin(M_PI * (double)m / 512.0));
    }
    unsigned short hs = f2bf(v);
    Sh[n * GLD + k] = hs;
    Sl[n * GLD + k] = f2bf(v - bf2f(hs));
}

// ---------------- laplacian_h with free-slip BC ------------------------------------------------
__global__ void lap_kernel(float* __restrict__ out, const float* __restrict__ f) {
    int y = blockIdx.x * blockDim.x + threadIdx.x;
    int x = blockIdx.y * blockDim.y + threadIdx.y;
    int c = blockIdx.z;
    if (x >= NXY || y >= NXY) return;
    const float* fp = f + (size_t)c * NXY * NXY;
    float* op = out + (size_t)c * NXY * NXY;
    float v;
    if (y == 0)            v = ZFBCf * (fp[x*NXY + 1]       - fp[x*NXY + 0]);
    else if (y == NXY-1)   v = ZFBCf * (fp[x*NXY + NXY-2]   - fp[x*NXY + NXY-1]);
    else if (x == 0)       v = ZFBCf * (fp[1*NXY + y]       - fp[0*NXY + y]);
    else if (x == NXY-1)   v = ZFBCf * (fp[(NXY-2)*NXY + y] - fp[(NXY-1)*NXY + y]);
    else v = fp[(x+1)*NXY+y] + fp[(x-1)*NXY+y] + fp[x*NXY+y+1] + fp[x*NXY+y-1] - 4.f*fp[x*NXY+y];
    op[x*NXY + y] = v;
}

// ---------------- interior RHS ------------------------------------------------------------------
__global__ void rhs_kernel(float* __restrict__ kq, const float* __restrict__ q,
                           const float* __restrict__ p, const float* __restrict__ L2,
                           const float* __restrict__ wind) {
    int y = blockIdx.x * blockDim.x + threadIdx.x;
    int x = blockIdx.y * blockDim.y + threadIdx.y;
    int c = blockIdx.z;
    if (x >= NXY || y >= NXY) return;
    size_t off = (size_t)c * NXY * NXY;
    float* outp = kq + off;
    if (x == 0 || x == NXY-1 || y == 0 || y == NXY-1) { outp[x*NXY + y] = 0.f; return; }
#define IDX(i,j) ((i)*NXY + (j))
    const float* f = q + off;
    const float* g = p + off;
    float fmm=f[IDX(x-1,y-1)], fm0=f[IDX(x-1,y)], fmp=f[IDX(x-1,y+1)];
    float f0m=f[IDX(x,  y-1)],                     f0p=f[IDX(x,  y+1)];
    float fpm=f[IDX(x+1,y-1)], fp0=f[IDX(x+1,y)], fpp=f[IDX(x+1,y+1)];
    float gmm=g[IDX(x-1,y-1)], gm0=g[IDX(x-1,y)], gmp=g[IDX(x-1,y+1)];
    float g0m=g[IDX(x,  y-1)], g00=g[IDX(x,  y)], g0p=g[IDX(x,  y+1)];
    float gpm=g[IDX(x+1,y-1)], gp0=g[IDX(x+1,y)], gpp=g[IDX(x+1,y+1)];
    float J1 = (fp0 - fm0) * (g0p - g0m) - (gp0 - gm0) * (f0p - f0m);
    float J2 = fp0 * (gpp - gpm) - fm0 * (gmp - gmm);
    float J3 = f0p * (gpp - gmp) - f0m * (gpm - gmm);
    float J4 = g0p * (fpp - fmp) - g0m * (fpm - fmm);
    float J5 = gp0 * (fpp - fpm) - gm0 * (fmp - fmm);
    float jac = (J1 + J2 - J3 + J4 - J5) * (1.0f / 12.0f);
    float lap2 = L2[off+IDX(x+1,y)] + L2[off+IDX(x-1,y)] + L2[off+IDX(x,y+1)] + L2[off+IDX(x,y-1)]
               - 4.f * L2[off+IDX(x,y)];
    float v = JACCf * jac - HYPCf * lap2;
    int l = c % NL3;
    if (l == 0)     v += wind[(x-1)*NIN + (y-1)];
    if (l == NL3-1) v += BFCf * (gp0 + gm0 + g0p + g0m - 4.f * g00);
    outp[IDX(x,y)] = v;
#undef IDX
}

// ---------------- layer->mode, writes bf16 hi/lo compact 512x512 (pads zeroed) -----------------
__global__ void l2m_kernel(unsigned short* __restrict__ Gh, unsigned short* __restrict__ Gl,
                           const float* __restrict__ kq, const float* __restrict__ Cl2m) {
    int ry = blockIdx.x * blockDim.x + threadIdx.x;
    int rx = blockIdx.y * blockDim.y + threadIdx.y;
    int e = blockIdx.z;
    size_t go = (size_t)(e * NL3) * GLD * GLD + (size_t)rx * GLD + ry;
    if (rx >= NIN || ry >= NIN) {
        for (int i = 0; i < 3; ++i) { Gh[go + (size_t)i*GLD*GLD] = 0; Gl[go + (size_t)i*GLD*GLD] = 0; }
        return;
    }
    size_t base = ((size_t)(e * NL3) * NXY + (rx + 1)) * NXY + (ry + 1);
    float f0 = kq[base];
    float f1 = kq[base + (size_t)NXY*NXY];
    float f2 = kq[base + 2*(size_t)NXY*NXY];
    float v[3];
    v[0] = Cl2m[0]*f0 + Cl2m[1]*f1 + Cl2m[2]*f2;
    v[1] = Cl2m[3]*f0 + Cl2m[4]*f1 + Cl2m[5]*f2;
    v[2] = Cl2m[6]*f0 + Cl2m[7]*f1 + Cl2m[8]*f2;
#pragma unroll
    for (int i = 0; i < 3; ++i) {
        unsigned short hs = f2bf(v[i]);
        Gh[go + (size_t)i*GLD*GLD] = hs;
        Gl[go + (size_t)i*GLD*GLD] = f2bf(v[i] - bf2f(hs));
    }
}

// ---------------- split-bf16 MFMA GEMM: out = store_T(A * S) -----------------------------------
// A row-major [12][512][512] (hi/lo), S symmetric [512][512] (hi/lo).
// Output written TRANSPOSED: out[n][m] = sum_k A[m][k] S[k][n]; optional helm divide; output
// either bf16 hi/lo pair (Ch/Cl) or fp32 (Cf).
#define SWZ(o) ((o) ^ ((((o) >> 7) & 7) << 4))
__global__ __launch_bounds__(256, 1) void gemm_dst(
    const unsigned short* __restrict__ Ah, const unsigned short* __restrict__ Al,
    const unsigned short* __restrict__ Sh, const unsigned short* __restrict__ Sl,
    unsigned short* __restrict__ Ch, unsigned short* __restrict__ Cl,
    float* __restrict__ Cf, const float* __restrict__ helm)
{
    __shared__ __attribute__((aligned(16))) unsigned short lds[2][4][8192]; // 128KB: [buf][AH,AL,BH,BL][128*64]
    const int b  = blockIdx.z;
    const int m0 = blockIdx.x << 7, n0 = blockIdx.y << 7;
    const int t  = threadIdx.x;
    const int w  = t >> 6, l = t & 63;
    const int wr = w >> 1, wc = w & 1;
    const int lr = l & 15, g = l >> 4;
    const unsigned short* Abh = Ah + (size_t)b * 262144;
    const unsigned short* Abl = Al + (size_t)b * 262144;

    int so[4]; size_t agb[4], bgb[4];
#pragma unroll
    for (int u = 0; u < 4; ++u) {
        int o = t*16 + u*4096;           // byte offset in 16KB plane
        so[u] = SWZ(o);
        int grow = o >> 7;               // 0..127
        int gcol = (o & 127) >> 1;       // 0..63 elements
        agb[u] = (size_t)(m0 + grow) * 512 + gcol;
        bgb[u] = (size_t)(n0 + grow) * 512 + gcol;
    }

    uint4 r_ah[4], r_al[4], r_bh[4], r_bl[4];
    auto LOAD = [&](int kt) {
#pragma unroll
        for (int u = 0; u < 4; ++u) {
            r_ah[u] = *(const uint4*)(Abh + agb[u] + kt*64);
            r_al[u] = *(const uint4*)(Abl + agb[u] + kt*64);
            r_bh[u] = *(const uint4*)(Sh  + bgb[u] + kt*64);
            r_bl[u] = *(const uint4*)(Sl  + bgb[u] + kt*64);
        }
    };
    auto STORE = [&](int buf) {
#pragma unroll
        for (int u = 0; u < 4; ++u) {
            *(uint4*)((char*)&lds[buf][0][0] + so[u]) = r_ah[u];
            *(uint4*)((char*)&lds[buf][1][0] + so[u]) = r_al[u];
            *(uint4*)((char*)&lds[buf][2][0] + so[u]) = r_bh[u];
            *(uint4*)((char*)&lds[buf][3][0] + so[u]) = r_bl[u];
        }
    };

    f32x4 acc[4][4] = {};
    int abyte[4], bbyte[4];
#pragma unroll
    for (int i = 0; i < 4; ++i) {
        abyte[i] = (wr*64 + i*16 + lr)*128 + g*16;
        bbyte[i] = (wc*64 + i*16 + lr)*128 + g*16;
    }

    LOAD(0); STORE(0);
    for (int it = 0; it < 8; ++it) {
        if (it < 7) LOAD(it + 1);
        __syncthreads();
        const int buf = it & 1;
#pragma unroll
        for (int kk = 0; kk < 2; ++kk) {
            bf16x8 fbh[4], fbl[4];
#pragma unroll
            for (int j = 0; j < 4; ++j) {
                int ob = SWZ(bbyte[j] + kk*64);
                fbh[j] = *(const bf16x8*)((const char*)&lds[buf][2][0] + ob);
                fbl[j] = *(const bf16x8*)((const char*)&lds[buf][3][0] + ob);
            }
#pragma unroll
            for (int i = 0; i < 4; ++i) {
                int oa = SWZ(abyte[i] + kk*64);
                bf16x8 fah = *(const bf16x8*)((const char*)&lds[buf][0][0] + oa);
                bf16x8 fal = *(const bf16x8*)((const char*)&lds[buf][1][0] + oa);
#pragma unroll
                for (int j = 0; j < 4; ++j) {
                    acc[i][j] = __builtin_amdgcn_mfma_f32_16x16x32_bf16(fah, fbh[j], acc[i][j], 0, 0, 0);
                    acc[i][j] = __builtin_amdgcn_mfma_f32_16x16x32_bf16(fah, fbl[j], acc[i][j], 0, 0, 0);
                    acc[i][j] = __builtin_amdgcn_mfma_f32_16x16x32_bf16(fal, fbh[j], acc[i][j], 0, 0, 0);
                    acc[i][j] = __builtin_amdgcn_mfma_f32_16x16x32_bf16(fal, fbl[j], acc[i][j], 0, 0, 0);
                }
            }
        }
        if (it < 7) STORE(buf ^ 1);
    }

    const int mode = b % NL3;
    const float* hp = helm ? (helm + (size_t)mode * NIN * NIN) : nullptr;
#pragma unroll
    for (int i = 0; i < 4; ++i) {
        int mmb = m0 + wr*64 + i*16 + 4*g;
#pragma unroll
        for (int j = 0; j < 4; ++j) {
            int nn = n0 + wc*64 + j*16 + lr;
            float v[4];
#pragma unroll
            for (int r = 0; r < 4; ++r) v[r] = acc[i][j][r];
            if (hp && nn < NIN) {
#pragma unroll
                for (int r = 0; r < 4; ++r)
                    if (mmb + r < NIN) v[r] /= hp[(size_t)nn*NIN + mmb + r];
            }
            size_t co = (size_t)b*262144 + (size_t)nn*512 + mmb;
            if (Cf) {
                f32x4 vv = {v[0], v[1], v[2], v[3]};
                *(f32x4*)(Cf + co) = vv;
            } else {
                unsigned int h01, h23, l01, l23;
                unsigned short hs0 = f2bf(v[0]), hs1 = f2bf(v[1]), hs2 = f2bf(v[2]), hs3 = f2bf(v[3]);
                unsigned short ls0 = f2bf(v[0]-bf2f(hs0)), ls1 = f2bf(v[1]-bf2f(hs1));
                unsigned short ls2 = f2bf(v[2]-bf2f(hs2)), ls3 = f2bf(v[3]-bf2f(hs3));
                h01 = (unsigned int)hs0 | ((unsigned int)hs1 << 16);
                h23 = (unsigned int)hs2 | ((unsigned int)hs3 << 16);
                l01 = (unsigned int)ls0 | ((unsigned int)ls1 << 16);
                l23 = (unsigned int)ls2 | ((unsigned int)ls3 << 16);
                *(uint2*)(Ch + co) = make_uint2(h01, h23);
                *(uint2*)(Cl + co) = make_uint2(l01, l23);
            }
        }
    }
}

// ---------------- per-(e,mode<2) partial sums of dp_modes --------------------------------------
__global__ void mean_kernel(float* __restrict__ partial, const float* __restrict__ G) {
    int gy = blockIdx.y;
    int e = gy >> 1, m = gy & 1;
    const float* g = G + (size_t)(e * NL3 + m) * GLD * GLD;
    float s = 0.f;
    for (int idx = blockIdx.x * 256 + threadIdx.x; idx < GLD*GLD; idx += 64 * 256)
        s += g[idx];
    __shared__ float red[256];
    red[threadIdx.x] = s; __syncthreads();
    for (int w = 128; w >= 1; w >>= 1) {
        if (threadIdx.x < w) red[threadIdx.x] += red[threadIdx.x + w];
        __syncthreads();
    }
    if (threadIdx.x == 0) partial[gy * 64 + blockIdx.x] = red[0];
}

__global__ void dalpha_kernel(float* __restrict__ dal, const float* __restrict__ partial,
                              const float* __restrict__ alpha) {
    int t = threadIdx.x;
    if (t >= 8) return;
    int e = t >> 1, i = t & 1;
    float s0 = 0.f, s1 = 0.f;
    for (int bk = 0; bk < 64; ++bk) { s0 += partial[(e*2+0)*64 + bk]; s1 += partial[(e*2+1)*64 + bk]; }
    const float inv = 1.0f / ((float)NXY * (float)NXY);
    dal[t] = alpha[i*2+0] * (s0 * inv) + alpha[i*2+1] * (s1 * inv);
}

// ---------------- mode->layer -------------------------------------------------------------------
__global__ void m2l_kernel(float* __restrict__ kp, const float* __restrict__ G,
                           const float* __restrict__ dal, const float* __restrict__ hom,
                           const float* __restrict__ Cm2l) {
    int y = blockIdx.x * blockDim.x + threadIdx.x;
    int x = blockIdx.y * blockDim.y + threadIdx.y;
    int e = blockIdx.z;
    if (x >= NXY || y >= NXY) return;
    float mv[3];
    bool interior = (x >= 1 && x <= NIN && y >= 1 && y <= NIN);
#pragma unroll
    for (int i = 0; i < 3; ++i)
        mv[i] = interior ? G[(size_t)(e*NL3 + i) * GLD * GLD + (size_t)(x-1) * GLD + (y-1)] : 0.f;
    float h0 = hom[(size_t)x * NXY + y];
    float h1 = hom[(size_t)NXY*NXY + (size_t)x * NXY + y];
    mv[0] += dal[e*2 + 0] * h0;
    mv[1] += dal[e*2 + 1] * h1;
#pragma unroll
    for (int l = 0; l < 3; ++l)
        kp[((size_t)(e*NL3 + l) * NXY + x) * NXY + y] =
            Cm2l[l*3+0]*mv[0] + Cm2l[l*3+1]*mv[1] + Cm2l[l*3+2]*mv[2];
}

// ---------------- boundary dq -------------------------------------------------------------------
__global__ void bound_kernel(float* __restrict__ kq, const float* __restrict__ kp,
                             const float* __restrict__ Amat) {
    int pos = blockIdx.x * 256 + threadIdx.x;
    int e = blockIdx.y;
    if (pos >= 2048) return;
    int x, y, xn, yn;
    if (pos < NIN)            { x = 0;      y = pos + 1;        xn = 1;      yn = y; }
    else if (pos < 2*NIN)     { x = NXY-1;  y = pos - NIN + 1;  xn = NXY-2;  yn = y; }
    else if (pos < 2*NIN+NXY) { x = pos - 2*NIN;       y = 0;      xn = x; yn = 1; }
    else                      { x = pos - (2*NIN+NXY); y = NXY-1;  xn = x; yn = NXY-2; }
    float dpb[3], lpb[3];
#pragma unroll
    for (int j = 0; j < 3; ++j) {
        const float* f = kp + (size_t)(e*NL3 + j) * NXY * NXY;
        float c = f[(size_t)x * NXY + y];
        float nb = f[(size_t)xn * NXY + yn];
        dpb[j] = c;
        lpb[j] = ZFBCf * INVF0DX2f * (nb - c);
    }
#pragma unroll
    for (int l = 0; l < 3; ++l) {
        float v = lpb[l] - (Amat[l*3+0]*dpb[0] + Amat[l*3+1]*dpb[1] + Amat[l*3+2]*dpb[2]);
        kq[((size_t)(e*NL3 + l) * NXY + x) * NXY + y] = v;
    }
}

// ---------------- fused RK4 update: o1 = (acc? o1:x) + c1*dt*k ; o2 = x + c2*dt*k ---------------
__global__ void rk_fused(float4* __restrict__ o1, float4* __restrict__ o2,
                         const float4* __restrict__ x, const float4* __restrict__ k,
                         float c1, float c2, int accumulate,
                         const float* __restrict__ t, int s, long n4) {
    float dt = t[s+1] - t[s];
    float a1 = c1 * dt, a2 = c2 * dt;
    for (long i = (long)blockIdx.x * blockDim.x + threadIdx.x; i < n4;
         i += (long)gridDim.x * blockDim.x) {
        float4 kk = k[i], xx = x[i];
        float4 b0 = accumulate ? o1[i] : xx;
        o1[i] = make_float4(b0.x + a1*kk.x, b0.y + a1*kk.y, b0.z + a1*kk.z, b0.w + a1*kk.w);
        if (o2) o2[i] = make_float4(xx.x + a2*kk.x, xx.y + a2*kk.y, xx.z + a2*kk.z, xx.w + a2*kk.w);
    }
}

__global__ void copy_kernel(float4* __restrict__ out, const float4* __restrict__ in, long n4) {
    for (long i = (long)blockIdx.x * blockDim.x + threadIdx.x; i < n4;
         i += (long)gridDim.x * blockDim.x)
        out[i] = in[i];
}

// ===============================================================================================
extern "C" void kernel_launch(void* const* d_in, const int* in_sizes, int n_in,
                              void* d_out, int out_size, void* d_ws, size_t ws_size,
                              hipStream_t stream) {
    const float* y0    = (const float*)d_in[0];
    const float* tarr  = (const float*)d_in[1];
    const float* Amat  = (const float*)d_in[2];
    const float* Cl2m  = (const float*)d_in[3];
    const float* Cm2l  = (const float*)d_in[4];
    const float* helm  = (const float*)d_in[5];
    const float* alpha = (const float*)d_in[6];
    const float* hom   = (const float*)d_in[7];
    const float* wind  = (const float*)d_in[8];
    float* out = (float*)d_out;
    char* base = (char*)d_ws;

    unsigned short* Sh = (unsigned short*)base;                       // 512 KB
    unsigned short* Sl = (unsigned short*)(base + 512*1024);          // 512 KB
    float* ytmp = (float*)(base + 1024*1024);                         // 2*FS floats
    float* kbuf = ytmp + 2*FS;                                        // 2*FS floats
    char*  REGb = (char*)(kbuf + 2*FS);                               // 2*FS floats worth of bytes
    float* lapA = (float*)REGb;
    float* lapB = lapA + FS;
    unsigned short* P0h = (unsigned short*)REGb;
    unsigned short* P0l = P0h + GSZ;
    unsigned short* P1h = P0l + GSZ;
    unsigned short* P1l = P1h + GSZ;
    float* R4 = (float*)REGb;                                         // aliases P0h..P0l (pass order safe)
    float* partial = (float*)(REGb + (size_t)2*FS*sizeof(float));
    float* dal = partial + 512;

    const dim3 bSt(64, 4, 1);
    const dim3 gSt((NXY + 63)/64, (NXY + 3)/4, NB);
    const dim3 gSt4((NXY + 63)/64, (NXY + 3)/4, NE4);
    const dim3 gL2M(8, 128, NE4);
    const dim3 gG(4, 4, NB);
    const long n4 = 2*FS/4;

    initS_kernel<<<dim3(2, GLD), 256, 0, stream>>>(Sh, Sl);
    copy_kernel<<<1024, 256, 0, stream>>>((float4*)out, (const float4*)y0, n4);

    auto deriv = [&](const float* y, float* k) {
        const float* q = y;  const float* p = y + FS;
        float* kq = k;       float* kp = k + FS;
        lap_kernel<<<gSt, bSt, 0, stream>>>(lapA, p);
        lap_kernel<<<gSt, bSt, 0, stream>>>(lapB, lapA);
        rhs_kernel<<<gSt, bSt, 0, stream>>>(kq, q, p, lapB, wind);
        l2m_kernel<<<gL2M, bSt, 0, stream>>>(P0h, P0l, kq, Cl2m);
        gemm_dst<<<gG, 256, 0, stream>>>(P0h, P0l, Sh, Sl, P1h, P1l, nullptr, nullptr);
        gemm_dst<<<gG, 256, 0, stream>>>(P1h, P1l, Sh, Sl, P0h, P0l, nullptr, helm);
        gemm_dst<<<gG, 256, 0, stream>>>(P0h, P0l, Sh, Sl, P1h, P1l, nullptr, nullptr);
        gemm_dst<<<gG, 256, 0, stream>>>(P1h, P1l, Sh, Sl, nullptr, nullptr, R4, nullptr);
        mean_kernel<<<dim3(64, 8), 256, 0, stream>>>(partial, R4);
        dalpha_kernel<<<1, 64, 0, stream>>>(dal, partial, alpha);
        m2l_kernel<<<gSt4, bSt, 0, stream>>>(kp, R4, dal, hom, Cm2l);
        bound_kernel<<<dim3(8, NE4), 256, 0, stream>>>(kq, kp, Amat);
    };

    for (int s = 0; s < NSTEPS; ++s) {
        float* ycur  = out + (size_t)s * 2 * FS;
        float* ynext = out + (size_t)(s + 1) * 2 * FS;
        deriv(ycur, kbuf);
        rk_fused<<<1024, 256, 0, stream>>>((float4*)ynext, (float4*)ytmp, (const float4*)ycur,
                                           (const float4*)kbuf, 1.f/6.f, 0.5f, 0, tarr, s, n4);
        deriv(ytmp, kbuf);
        rk_fused<<<1024, 256, 0, stream>>>((float4*)ynext, (float4*)ytmp, (const float4*)ycur,
                                           (const float4*)kbuf, 2.f/6.f, 0.5f, 1, tarr, s, n4);
        deriv(ytmp, kbuf);
        rk_fused<<<1024, 256, 0, stream>>>((float4*)ynext, (float4*)ytmp, (const float4*)ycur,
                                           (const float4*)kbuf, 2.f/6.f, 1.0f, 1, tarr, s, n4);
        deriv(ytmp, kbuf);
        rk_fused<<<1024, 256, 0, stream>>>((float4*)ynext, nullptr, (const float4*)ycur,
                                           (const float4*)kbuf, 1.f/6.f, 0.f, 1, tarr, s, n4);
    }
}